// Round 2
// baseline (333.089 us; speedup 1.0000x reference)
//
#include <hip/hip_runtime.h>

// Problem constants (fixed by reference: B=32,D=64,H=32,W=32,K=2048)
#define N_PIX 32768   // B*H*W
#define DIM   64
#define KCODE 2048

// ---------------------------------------------------------------------------
// Kernel A: e_sq[k] = sum_d codebook[k][d]^2
// ---------------------------------------------------------------------------
__global__ void esq_kernel(const float* __restrict__ cb, float* __restrict__ esq) {
    int k = blockIdx.x * blockDim.x + threadIdx.x;
    if (k >= KCODE) return;
    const float4* row = (const float4*)(cb + (size_t)k * DIM);
    float s0 = 0.f, s1 = 0.f, s2 = 0.f, s3 = 0.f;
#pragma unroll
    for (int i = 0; i < DIM / 4; ++i) {
        float4 v = row[i];
        s0 = fmaf(v.x, v.x, s0);
        s1 = fmaf(v.y, v.y, s1);
        s2 = fmaf(v.z, v.z, s2);
        s3 = fmaf(v.w, v.w, s3);
    }
    esq[k] = (s0 + s1) + (s2 + s3);
}

// ---------------------------------------------------------------------------
// Kernel B: per-pixel, per-K-chunk partial argmin of (e_sq - 2*dot(x,e)).
//   block=256 (4 waves), grid=(N/256, nchunks).
//   __launch_bounds__(256,2): min 2 waves/EU -> 128-VGPR budget, so the
//   x[16] float4 tile (64 VGPRs) stays register-resident (round-1 failure:
//   44-VGPR budget forced the compiler to re-load x inside the c-loop).
//   c-loop unrolled x2 with independent accumulators for load/FMA overlap.
// ---------------------------------------------------------------------------
__global__ __launch_bounds__(256, 2)
void dist_kernel(const float* __restrict__ laten, const float* __restrict__ cb,
                 const float* __restrict__ esq,
                 float* __restrict__ pdist, int* __restrict__ pidx,
                 int kper, int nchunks) {
    const int n  = blockIdx.x * 256 + threadIdx.x;  // pixel index (b*1024 + hw)
    const int b  = n >> 10;
    const int hw = n & 1023;

    // x[d] = laten[b][d][h][w]; coalesced across lanes (hw contiguous).
    const float* base = laten + (((size_t)b * DIM) << 10) + hw;
    float4 x[16];
#pragma unroll
    for (int i = 0; i < 16; ++i) {
        x[i].x = base[(size_t)(4 * i + 0) << 10];
        x[i].y = base[(size_t)(4 * i + 1) << 10];
        x[i].z = base[(size_t)(4 * i + 2) << 10];
        x[i].w = base[(size_t)(4 * i + 3) << 10];
    }

    const int c0 = blockIdx.y * kper;
    float best  = 3.4e38f;
    int   bestI = c0;

    for (int c = c0; c < c0 + kper; c += 2) {
        const float4* r0 = (const float4*)(cb + ((size_t)c << 6));       // uniform addr
        const float4* r1 = (const float4*)(cb + ((size_t)(c + 1) << 6));
        float a0 = 0.f, a1 = 0.f, a2 = 0.f, a3 = 0.f;
        float b0 = 0.f, b1 = 0.f, b2 = 0.f, b3 = 0.f;
#pragma unroll
        for (int i = 0; i < 16; ++i) {
            float4 v0 = r0[i];
            float4 v1 = r1[i];
            a0 = fmaf(v0.x, x[i].x, a0);
            a1 = fmaf(v0.y, x[i].y, a1);
            a2 = fmaf(v0.z, x[i].z, a2);
            a3 = fmaf(v0.w, x[i].w, a3);
            b0 = fmaf(v1.x, x[i].x, b0);
            b1 = fmaf(v1.y, x[i].y, b1);
            b2 = fmaf(v1.z, x[i].z, b2);
            b3 = fmaf(v1.w, x[i].w, b3);
        }
        float d0 = esq[c]     - 2.0f * ((a0 + a1) + (a2 + a3));
        float d1 = esq[c + 1] - 2.0f * ((b0 + b1) + (b2 + b3));
        // Sequential strict-< updates preserve "first minimum" tie semantics.
        if (d0 < best) { best = d0; bestI = c; }
        if (d1 < best) { best = d1; bestI = c + 1; }
    }
    pdist[(size_t)n * nchunks + blockIdx.y] = best;
    pidx [(size_t)n * nchunks + blockIdx.y] = bestI;
}

// ---------------------------------------------------------------------------
// Kernel C (fused merge + gather):
//   merge 8 chunk partials -> final idx; out0[n] = (float)idx;
//   out1[b][d][h][w] = codebook[idx][d]  (writes coalesced across hw).
// ---------------------------------------------------------------------------
__global__ __launch_bounds__(256)
void finish_kernel(const float* __restrict__ cb,
                   const float* __restrict__ pdist, const int* __restrict__ pidx,
                   float* __restrict__ out0, float* __restrict__ out1,
                   int nchunks) {
    const int n = blockIdx.x * 256 + threadIdx.x;

    float best;
    int   bi;
    if (nchunks == 8) {
        const float4* pd = (const float4*)(pdist + ((size_t)n << 3));
        const int4*   pi = (const int4*)  (pidx  + ((size_t)n << 3));
        float4 da = pd[0], db = pd[1];
        int4   ia = pi[0], ib = pi[1];
        best = da.x; bi = ia.x;
        if (da.y < best) { best = da.y; bi = ia.y; }
        if (da.z < best) { best = da.z; bi = ia.z; }
        if (da.w < best) { best = da.w; bi = ia.w; }
        if (db.x < best) { best = db.x; bi = ib.x; }
        if (db.y < best) { best = db.y; bi = ib.y; }
        if (db.z < best) { best = db.z; bi = ib.z; }
        if (db.w < best) { best = db.w; bi = ib.w; }
    } else {
        best = pdist[(size_t)n * nchunks];
        bi   = pidx [(size_t)n * nchunks];
        for (int j = 1; j < nchunks; ++j) {
            float dj = pdist[(size_t)n * nchunks + j];
            int   ij = pidx [(size_t)n * nchunks + j];
            if (dj < best) { best = dj; bi = ij; }
        }
    }
    out0[n] = (float)bi;

    const int b  = n >> 10;
    const int hw = n & 1023;
    const float4* row = (const float4*)(cb + ((size_t)bi << 6));  // L2-resident
    float* o = out1 + (((size_t)b * DIM) << 10) + hw;
#pragma unroll
    for (int i = 0; i < 16; ++i) {
        float4 v = row[i];
        o[(size_t)(4 * i + 0) << 10] = v.x;
        o[(size_t)(4 * i + 1) << 10] = v.y;
        o[(size_t)(4 * i + 2) << 10] = v.z;
        o[(size_t)(4 * i + 3) << 10] = v.w;
    }
}

// ---------------------------------------------------------------------------
extern "C" void kernel_launch(void* const* d_in, const int* in_sizes, int n_in,
                              void* d_out, int out_size, void* d_ws, size_t ws_size,
                              hipStream_t stream) {
    const float* laten = (const float*)d_in[0];   // (32,64,32,32) fp32
    const float* cb    = (const float*)d_in[1];   // (2048,64) fp32

    float* out0 = (float*)d_out;                  // indices as float, N_PIX elems
    float* out1 = (float*)d_out + N_PIX;          // quant_laten, 2M elems

    // ws floats needed = 2048 (esq) + N*nc (pdist) + N*nc (pidx)
    int nchunks = 8;
    while (nchunks > 1 &&
           (size_t)(2048 + (size_t)N_PIX * nchunks * 2) * 4 > ws_size)
        nchunks >>= 1;
    const int kper = KCODE / nchunks;

    float* esq   = (float*)d_ws;                          // 2048
    float* pdist = esq + 2048;                            // N*nchunks
    int*   pidx  = (int*)(pdist + (size_t)N_PIX * nchunks);

    esq_kernel<<<KCODE / 256, 256, 0, stream>>>(cb, esq);

    dim3 gridB(N_PIX / 256, nchunks);
    dist_kernel<<<gridB, 256, 0, stream>>>(laten, cb, esq, pdist, pidx, kper, nchunks);

    finish_kernel<<<N_PIX / 256, 256, 0, stream>>>(cb, pdist, pidx, out0, out1, nchunks);
}

// Round 3
// 173.970 us; speedup vs baseline: 1.9146x; 1.9146x over previous
//
#include <hip/hip_runtime.h>

// Problem constants (fixed by reference: B=32,D=64,H=32,W=32,K=2048)
#define N_PIX 32768   // B*H*W
#define DIM   64
#define KCODE 2048

// ---------------------------------------------------------------------------
// Kernel A: e_sq[k] = sum_d codebook[k][d]^2
// ---------------------------------------------------------------------------
__global__ void esq_kernel(const float* __restrict__ cb, float* __restrict__ esq) {
    int k = blockIdx.x * blockDim.x + threadIdx.x;
    if (k >= KCODE) return;
    const float4* row = (const float4*)(cb + (size_t)k * DIM);
    float s0 = 0.f, s1 = 0.f, s2 = 0.f, s3 = 0.f;
#pragma unroll
    for (int i = 0; i < DIM / 4; ++i) {
        float4 v = row[i];
        s0 = fmaf(v.x, v.x, s0);
        s1 = fmaf(v.y, v.y, s1);
        s2 = fmaf(v.z, v.z, s2);
        s3 = fmaf(v.w, v.w, s3);
    }
    esq[k] = (s0 + s1) + (s2 + s3);
}

// ---------------------------------------------------------------------------
// Kernel B: register-blocked fp32 GEMM (dist = esq - 2*x.e) with fused argmin.
//   Block 256 thr = 4 waves as 2x2, C-tile 128(M px) x 128(N codes), K=DIM=64.
//   Each lane owns an 8x8 acc patch -> 64 FMAs per 16 LDS dwords (4x b128).
//   A-tile rows (fixed d, 128 px) are contiguous in NCHW laten: coalesced.
//   B-tile staged transposed (k-major) via float4 loads + 4x b32 scatter
//   (consecutive lanes -> consecutive n: conflict-free).
//   Epilogue: per-lane argmin over its 8 codes, LDS tree over 16 n-octets
//   (red scratch ALIASES Bs between barriers), per-N-tile partial -> ws.
// ---------------------------------------------------------------------------
__global__ __launch_bounds__(256, 2)
void gemm_argmin_kernel(const float* __restrict__ laten, const float* __restrict__ cb,
                        const float* __restrict__ esq,
                        float* __restrict__ pdist, int* __restrict__ pidx,
                        int tilesPerBlock, int nch) {
    __shared__ float As[DIM * 128];   // [k][m]  32 KB
    __shared__ float Bs[DIM * 128];   // [k][n]  32 KB  (epilogue aliases as red)
    float* redD = Bs;                 // [128][16] dist partials
    int*   redI = (int*)(Bs + 2048);  // [128][16] idx partials

    const int tid   = threadIdx.x;
    const int m0pix = blockIdx.x * 128;           // 128-aligned: never crosses b
    const int b     = m0pix >> 10;
    const int hw0   = m0pix & 1023;

    // ---- stage A once (tile-invariant across n-tiles) ----
    const float* abase = laten + (((size_t)b * DIM) << 10) + hw0;
#pragma unroll
    for (int i = 0; i < 8; ++i) {
        int f = tid + i * 256;                    // float4 id, 2048 total
        int k = f >> 5, pos = (f & 31) * 4;       // 32 float4 per row
        float4 v = *(const float4*)(abase + ((size_t)k << 10) + pos);
        *(float4*)(As + k * 128 + pos) = v;
    }

    const int w    = tid >> 6, lane = tid & 63;
    const int wm   = w & 1,    wn   = w >> 1;     // 2x2 wave grid
    const int mo   = lane & 7, no   = lane >> 3;  // 8x8 lane grid
    const int mloc = wm * 64 + mo * 8;            // lane's m base (local)
    const int nloc = wn * 64 + no * 8;            // lane's n base (local)

    float bestR = 3.4e38f;                        // running best (reducer thr)
    int   bidR  = 0;

    for (int t = 0; t < tilesPerBlock; ++t) {
        const int n0 = (blockIdx.y * tilesPerBlock + t) * 128;

        __syncthreads();   // A staged (t=0) / red consumed (t>0): Bs writable

        // ---- stage B transposed: Bs[k][n] = cb[n0+n][k] ----
#pragma unroll
        for (int i = 0; i < 8; ++i) {
            int f = tid + i * 256;
            int n = f & 127, k4 = (f >> 7) * 4;
            float4 v = *(const float4*)(cb + (size_t)(n0 + n) * DIM + k4);
            Bs[(k4 + 0) * 128 + n] = v.x;
            Bs[(k4 + 1) * 128 + n] = v.y;
            Bs[(k4 + 2) * 128 + n] = v.z;
            Bs[(k4 + 3) * 128 + n] = v.w;
        }
        __syncthreads();

        // ---- main loop: 64 k-steps, 64 FMA / 4 ds_read_b128 per step ----
        float acc[8][8];
#pragma unroll
        for (int i = 0; i < 8; ++i)
#pragma unroll
            for (int j = 0; j < 8; ++j) acc[i][j] = 0.f;

#pragma unroll 4
        for (int k = 0; k < DIM; ++k) {
            const float4 a0 = *(const float4*)(As + k * 128 + mloc);
            const float4 a1 = *(const float4*)(As + k * 128 + mloc + 4);
            const float4 b0 = *(const float4*)(Bs + k * 128 + nloc);
            const float4 b1 = *(const float4*)(Bs + k * 128 + nloc + 4);
            const float av[8] = {a0.x, a0.y, a0.z, a0.w, a1.x, a1.y, a1.z, a1.w};
            const float bv[8] = {b0.x, b0.y, b0.z, b0.w, b1.x, b1.y, b1.z, b1.w};
#pragma unroll
            for (int i = 0; i < 8; ++i)
#pragma unroll
                for (int j = 0; j < 8; ++j)
                    acc[i][j] = fmaf(av[i], bv[j], acc[i][j]);
        }

        __syncthreads();   // all Bs reads done: red may overwrite

        // ---- per-lane argmin over its 8 codes (ascending n, strict <) ----
        const float4 e0 = *(const float4*)(esq + n0 + nloc);
        const float4 e1 = *(const float4*)(esq + n0 + nloc + 4);
        const float ev[8] = {e0.x, e0.y, e0.z, e0.w, e1.x, e1.y, e1.z, e1.w};
#pragma unroll
        for (int i = 0; i < 8; ++i) {
            float best = ev[0] - 2.0f * acc[i][0];
            int   bi   = n0 + nloc;
#pragma unroll
            for (int j = 1; j < 8; ++j) {
                float d = ev[j] - 2.0f * acc[i][j];
                if (d < best) { best = d; bi = n0 + nloc + j; }
            }
            redD[(mloc + i) * 16 + wn * 8 + no] = best;
            redI[(mloc + i) * 16 + wn * 8 + no] = bi;
        }
        __syncthreads();

        // ---- reduce 16 n-octet partials per pixel (s ascending = n ascending)
        if (tid < 128) {
#pragma unroll
            for (int s = 0; s < 16; ++s) {
                float d  = redD[tid * 16 + s];
                int   ii = redI[tid * 16 + s];
                if (d < bestR) { bestR = d; bidR = ii; }
            }
        }
    }

    if (tid < 128) {
        pdist[(size_t)(m0pix + tid) * nch + blockIdx.y] = bestR;
        pidx [(size_t)(m0pix + tid) * nch + blockIdx.y] = bidR;
    }
}

// ---------------------------------------------------------------------------
// Kernel C (fused merge + gather):
//   merge nch chunk partials -> final idx; out0[n] = (float)idx;
//   out1[b][d][h][w] = codebook[idx][d]  (writes coalesced across hw).
// ---------------------------------------------------------------------------
__global__ __launch_bounds__(256)
void finish_kernel(const float* __restrict__ cb,
                   const float* __restrict__ pdist, const int* __restrict__ pidx,
                   float* __restrict__ out0, float* __restrict__ out1,
                   int nch) {
    const int n = blockIdx.x * 256 + threadIdx.x;

    float best = pdist[(size_t)n * nch];
    int   bi   = pidx [(size_t)n * nch];
    for (int j = 1; j < nch; ++j) {
        float dj = pdist[(size_t)n * nch + j];
        int   ij = pidx [(size_t)n * nch + j];
        if (dj < best) { best = dj; bi = ij; }   // chunks ascend in n: ties keep low idx
    }
    out0[n] = (float)bi;

    const int b  = n >> 10;
    const int hw = n & 1023;
    const float4* row = (const float4*)(cb + ((size_t)bi << 6));  // L2-resident
    float* o = out1 + (((size_t)b * DIM) << 10) + hw;
#pragma unroll
    for (int i = 0; i < 16; ++i) {
        float4 v = row[i];
        o[(size_t)(4 * i + 0) << 10] = v.x;
        o[(size_t)(4 * i + 1) << 10] = v.y;
        o[(size_t)(4 * i + 2) << 10] = v.z;
        o[(size_t)(4 * i + 3) << 10] = v.w;
    }
}

// ---------------------------------------------------------------------------
extern "C" void kernel_launch(void* const* d_in, const int* in_sizes, int n_in,
                              void* d_out, int out_size, void* d_ws, size_t ws_size,
                              hipStream_t stream) {
    const float* laten = (const float*)d_in[0];   // (32,64,32,32) fp32
    const float* cb    = (const float*)d_in[1];   // (2048,64) fp32

    float* out0 = (float*)d_out;                  // indices as float, N_PIX elems
    float* out1 = (float*)d_out + N_PIX;          // quant_laten, 2M elems

    // nch = number of 128-code N-chunks written to ws (16 ideal).
    // ws floats needed = 2048 (esq) + N_PIX*nch (pdist) + N_PIX*nch (pidx)
    int nch = 16;
    while (nch > 1 &&
           (size_t)(2048 + (size_t)N_PIX * nch * 2) * 4 > ws_size)
        nch >>= 1;
    const int tilesPerBlock = 16 / nch;

    float* esq   = (float*)d_ws;                          // 2048
    float* pdist = esq + 2048;                            // N_PIX*nch
    int*   pidx  = (int*)(pdist + (size_t)N_PIX * nch);

    esq_kernel<<<KCODE / 256, 256, 0, stream>>>(cb, esq);

    dim3 gridB(N_PIX / 128, nch);
    gemm_argmin_kernel<<<gridB, 256, 0, stream>>>(laten, cb, esq, pdist, pidx,
                                                  tilesPerBlock, nch);

    finish_kernel<<<N_PIX / 256, 256, 0, stream>>>(cb, pdist, pidx, out0, out1, nch);
}

// Round 4
// 139.669 us; speedup vs baseline: 2.3848x; 1.2456x over previous
//
#include <hip/hip_runtime.h>

// Problem constants (fixed by reference: B=32,D=64,H=32,W=32,K=2048)
#define N_PIX 32768   // B*H*W
#define DIM   64
#define KCODE 2048

typedef __attribute__((ext_vector_type(8))) short bf16x8;   // 8 bf16 = 4 VGPR (guide §3)
typedef __attribute__((ext_vector_type(4))) float f32x4;    // MFMA C/D

// bf16 round-to-nearest-even, done manually (deterministic, no header API risk)
__device__ inline unsigned short f2bf(float v) {
    unsigned int u = __float_as_uint(v);
    return (unsigned short)((u + 0x7FFFu + ((u >> 16) & 1u)) >> 16);
}
__device__ inline float bf2f(unsigned short b) {
    return __uint_as_float(((unsigned int)b) << 16);
}

// ---------------------------------------------------------------------------
// Split laten into 3 bf16 planes (h/m/l), stored FRAGMENT-MAJOR:
//   unit(plane, mtile, kb) = 256B block = [m 0..15][j 0..7] bf16,
//   so an MFMA A-fragment load is base + lane*16 (fully coalesced dwordx4).
//   x = h + m + l with representation error ~2^-27|x|.
// ---------------------------------------------------------------------------
__global__ __launch_bounds__(256)
void convert_a(const float* __restrict__ laten, unsigned short* __restrict__ Ag) {
    const int p  = blockIdx.x * 256 + threadIdx.x;     // pixel id
    const int b  = p >> 10, hw = p & 1023;
    const float* src = laten + (((size_t)b << 6) << 10) + hw;
    const int mtile = p >> 4, mi = p & 15;
    char* outb = (char*)Ag;
#pragma unroll
    for (int kb = 0; kb < 8; ++kb) {
        alignas(16) unsigned short hv[8], mv[8], lv[8];
#pragma unroll
        for (int j = 0; j < 8; ++j) {
            float v = src[(size_t)(kb * 8 + j) << 10];   // coalesced across threads
            unsigned short h = f2bf(v);
            float r1 = v - bf2f(h);
            unsigned short m = f2bf(r1);
            unsigned short l = f2bf(r1 - bf2f(m));
            hv[j] = h; mv[j] = m; lv[j] = l;
        }
        size_t u = ((((size_t)mtile) * 8 + kb) << 8) + mi * 16;
        *(uint4*)(outb + u)           = *(uint4*)hv;     // plane 0 (h)
        *(uint4*)(outb + 4194304 + u) = *(uint4*)mv;     // plane 1 (m)
        *(uint4*)(outb + 8388608 + u) = *(uint4*)lv;     // plane 2 (l)
    }
}

// ---------------------------------------------------------------------------
// Same split for the codebook (B operand, unit = [n 0..15][j 0..7]) + e_sq.
// ---------------------------------------------------------------------------
__global__ __launch_bounds__(256)
void convert_b(const float* __restrict__ cb, unsigned short* __restrict__ Bg,
               float* __restrict__ esq) {
    const int n = blockIdx.x * 256 + threadIdx.x;       // code id, 0..2047
    const float* src = cb + (size_t)n * DIM;
    const int ntile = n >> 4, ni = n & 15;
    char* outb = (char*)Bg;
    float s = 0.f;
#pragma unroll
    for (int kb = 0; kb < 8; ++kb) {
        alignas(16) unsigned short hv[8], mv[8], lv[8];
#pragma unroll
        for (int j = 0; j < 8; ++j) {
            float v = src[kb * 8 + j];
            s = fmaf(v, v, s);
            unsigned short h = f2bf(v);
            float r1 = v - bf2f(h);
            unsigned short m = f2bf(r1);
            unsigned short l = f2bf(r1 - bf2f(m));
            hv[j] = h; mv[j] = m; lv[j] = l;
        }
        size_t u = ((((size_t)ntile) * 8 + kb) << 8) + ni * 16;
        *(uint4*)(outb + u)          = *(uint4*)hv;      // plane stride 128*8*256 = 256KB
        *(uint4*)(outb + 262144 + u) = *(uint4*)mv;
        *(uint4*)(outb + 524288 + u) = *(uint4*)lv;
    }
    esq[n] = s;
}

// ---------------------------------------------------------------------------
// MFMA dist kernel: block 256 = 2x2 waves, C-tile 128 px x 128 codes.
//   dot(x,e) = xh.eh + (xh.em + xm.eh) + (xh.el + xm.em + xl.eh): 6 bf16 MFMA
//   passes accumulated small->large into one fp32 acc (error ~5e-6, same
//   order as the fp32 reference's own accumulation error).
//   A-frags: direct global dwordx4 (fragment-major units). B: LDS, staged as
//   verbatim 16B copies (contiguous b128 reads, conflict-free).
//   Epilogue: per-lane argmin over 4 nt (ascending), stride-17 LDS scratch
//   (aliased into Bs), 128-thread final scan with index tie-break.
// ---------------------------------------------------------------------------
__global__ __launch_bounds__(256)
void mfma_dist_kernel(const unsigned short* __restrict__ Ag,
                      const unsigned short* __restrict__ Bg,
                      const float* __restrict__ esq,
                      float* __restrict__ pdist, int* __restrict__ pidx) {
    __shared__ uint4 Bs4[3072];   // 48 KB: 3 planes x 8 ntiles x 8 kb x 256B

    const int tid  = threadIdx.x;
    const int lane = tid & 63, wave = tid >> 6;
    const int wm = wave & 1, wn = wave >> 1;
    const int quad = lane >> 4, col = lane & 15;
    const int bx = blockIdx.x, by = blockIdx.y;
    const int mtile0 = bx * 8, ntile0 = by * 8;

    // ---- stage B: 3072 x 16B chunks, verbatim fragment-major copy ----
    const char* BgB = (const char*)Bg;
#pragma unroll
    for (int i = 0; i < 12; ++i) {
        int c = tid + i * 256;
        int unit = c >> 4, sub = c & 15;
        int pl = unit >> 6, rest = unit & 63;
        size_t g = ((((size_t)pl * 128 + ntile0 + (rest >> 3)) * 8 + (rest & 7)) << 8)
                 + (sub << 4);
        Bs4[c] = *(const uint4*)(BgB + g);
    }
    __syncthreads();

    f32x4 acc[4][4];
#pragma unroll
    for (int i = 0; i < 4; ++i)
#pragma unroll
        for (int j = 0; j < 4; ++j) acc[i][j] = {0.f, 0.f, 0.f, 0.f};

    const char* AgB = (const char*)Ag;
    const char* BsB = (const char*)Bs4;
    // pass order small->large magnitude: hl, lh, mm, hm, mh, hh
    const int paArr[6] = {0, 2, 1, 0, 1, 0};
    const int pbArr[6] = {2, 0, 1, 1, 0, 0};

#pragma unroll
    for (int pass = 0; pass < 6; ++pass) {
        const size_t aPl = (size_t)paArr[pass] * 4194304;
        const int    bPl = pbArr[pass] * 16384;
#pragma unroll
        for (int ks = 0; ks < 2; ++ks) {
            bf16x8 af[4], bfr[4];
#pragma unroll
            for (int mt = 0; mt < 4; ++mt) {
                size_t off = aPl + (size_t)(mtile0 + wm * 4 + mt) * 2048
                           + ks * 1024 + lane * 16;
                af[mt] = *(const bf16x8*)(AgB + off);   // coalesced 1KB/wave
            }
#pragma unroll
            for (int nt = 0; nt < 4; ++nt) {
                int off = bPl + (wn * 4 + nt) * 2048 + ks * 1024 + lane * 16;
                bfr[nt] = *(const bf16x8*)(BsB + off);  // contiguous ds_read_b128
            }
#pragma unroll
            for (int mt = 0; mt < 4; ++mt)
#pragma unroll
                for (int nt = 0; nt < 4; ++nt)
                    acc[mt][nt] = __builtin_amdgcn_mfma_f32_16x16x32_bf16(
                        af[mt], bfr[nt], acc[mt][nt], 0, 0, 0);
        }
    }

    __syncthreads();                    // all Bs reads done: alias as scratch
    float* redD = (float*)Bs4;          // [2][128][17] padded: conflict-free
    int*   redI = (int*)Bs4 + 4352;

    const int n0 = by * 128;
    const int nb = n0 + wn * 64 + col;
    float esqv[4];
#pragma unroll
    for (int nt = 0; nt < 4; ++nt) esqv[nt] = esq[nb + nt * 16];

    // C/D layout (m89-verified): col = lane&15, row = quad*4 + reg
#pragma unroll
    for (int mt = 0; mt < 4; ++mt) {
#pragma unroll
        for (int reg = 0; reg < 4; ++reg) {
            float d = fmaf(-2.f, acc[mt][0][reg], esqv[0]);
            int   i = nb;
            float d1 = fmaf(-2.f, acc[mt][1][reg], esqv[1]);
            if (d1 < d) { d = d1; i = nb + 16; }
            float d2 = fmaf(-2.f, acc[mt][2][reg], esqv[2]);
            if (d2 < d) { d = d2; i = nb + 32; }
            float d3 = fmaf(-2.f, acc[mt][3][reg], esqv[3]);
            if (d3 < d) { d = d3; i = nb + 48; }
            int mloc = wm * 64 + mt * 16 + quad * 4 + reg;
            int off = (wn * 128 + mloc) * 17 + col;
            redD[off] = d;
            redI[off] = i;
        }
    }
    __syncthreads();

    if (tid < 128) {
        float best = 3.4e38f; int bi = 0;
#pragma unroll
        for (int h = 0; h < 2; ++h)
#pragma unroll
            for (int c = 0; c < 16; ++c) {
                int off = (h * 128 + tid) * 17 + c;
                float d = redD[off]; int i = redI[off];
                // index tie-break: cols interleave n, must pick lowest index
                if (d < best || (d == best && i < bi)) { best = d; bi = i; }
            }
        size_t pix = (size_t)bx * 128 + tid;
        pdist[pix * 16 + by] = best;
        pidx [pix * 16 + by] = bi;
    }
}

// ---------------------------------------------------------------------------
// Fused merge + gather: merge 16 chunk partials -> idx; out0 = (float)idx;
// out1[b][d][h][w] = codebook[idx][d] from the ORIGINAL fp32 codebook (exact).
// ---------------------------------------------------------------------------
__global__ __launch_bounds__(256)
void finish_kernel(const float* __restrict__ cb,
                   const float* __restrict__ pdist, const int* __restrict__ pidx,
                   float* __restrict__ out0, float* __restrict__ out1,
                   int nch) {
    const int n = blockIdx.x * 256 + threadIdx.x;

    float best = pdist[(size_t)n * nch];
    int   bi   = pidx [(size_t)n * nch];
    for (int j = 1; j < nch; ++j) {
        float dj = pdist[(size_t)n * nch + j];
        int   ij = pidx [(size_t)n * nch + j];
        if (dj < best || (dj == best && ij < bi)) { best = dj; bi = ij; }
    }
    out0[n] = (float)bi;

    const int b  = n >> 10;
    const int hw = n & 1023;
    const float4* row = (const float4*)(cb + ((size_t)bi << 6));  // L2-resident
    float* o = out1 + (((size_t)b * DIM) << 10) + hw;
#pragma unroll
    for (int i = 0; i < 16; ++i) {
        float4 v = row[i];
        o[(size_t)(4 * i + 0) << 10] = v.x;
        o[(size_t)(4 * i + 1) << 10] = v.y;
        o[(size_t)(4 * i + 2) << 10] = v.z;
        o[(size_t)(4 * i + 3) << 10] = v.w;
    }
}

// ---------------------------------------------------------------------------
extern "C" void kernel_launch(void* const* d_in, const int* in_sizes, int n_in,
                              void* d_out, int out_size, void* d_ws, size_t ws_size,
                              hipStream_t stream) {
    const float* laten = (const float*)d_in[0];   // (32,64,32,32) fp32
    const float* cb    = (const float*)d_in[1];   // (2048,64) fp32

    float* out0 = (float*)d_out;                  // indices as float, N_PIX
    float* out1 = (float*)d_out + N_PIX;          // quant_laten, 2M

    // ws layout (bytes):
    //   esq    2048 f               (8 KB)
    //   pdist  N_PIX*16 f           (2 MB)
    //   pidx   N_PIX*16 i           (2 MB)
    //   Ag     3 planes * 2048 mtiles * 8 kb * 256B = 12 MB   (16B-aligned)
    //   Bg     3 planes * 128 ntiles * 8 kb * 256B  = 768 KB
    float* esq   = (float*)d_ws;
    float* pdist = esq + 2048;
    int*   pidx  = (int*)(pdist + (size_t)N_PIX * 16);
    unsigned short* Ag = (unsigned short*)(pidx + (size_t)N_PIX * 16);
    unsigned short* Bg = Ag + 6291456;            // 12 MB / 2B

    convert_a<<<N_PIX / 256, 256, 0, stream>>>(laten, Ag);
    convert_b<<<KCODE / 256, 256, 0, stream>>>(cb, Bg, esq);

    dim3 gridD(N_PIX / 128, 16);
    mfma_dist_kernel<<<gridD, 256, 0, stream>>>(Ag, Bg, esq, pdist, pidx);

    finish_kernel<<<N_PIX / 256, 256, 0, stream>>>(cb, pdist, pidx, out0, out1, 16);
}